// Round 19
// baseline (340.590 us; speedup 1.0000x reference)
//
#include <hip/hip_runtime.h>
#include <hip/hip_fp8.h>
#include <math.h>

#define NV 4096
#define NNL ((size_t)NV * NV)
#define BM 128
#define BK 32
#define NKT (NV / BK)

typedef __bf16 bf16_t;
typedef __bf16 bf16x4 __attribute__((ext_vector_type(4)));
typedef __bf16 bf16x8 __attribute__((ext_vector_type(8)));
typedef float f32x4 __attribute__((ext_vector_type(4)));
typedef long i64_t;
typedef unsigned char u8_t;

struct FCF { float c1[4], c2[4], c3[4], c4[4], cd[4]; };

__device__ __forceinline__ u8_t f32_to_e4m3(float v) {
  return (u8_t)__hip_cvt_float_to_fp8(v, __HIP_SATFINITE, __HIP_E4M3);
}

// ---------------------------------------------------------------------------
// Init: T1 = L - I  (bf16 plane + fp8-e4m3 plane for GEMM operands)
// ---------------------------------------------------------------------------
__global__ __launch_bounds__(256) void init_kernel(const float* __restrict__ L,
                                                   bf16_t* __restrict__ T1,
                                                   u8_t* __restrict__ T1f8) {
  const size_t stride = (size_t)gridDim.x * blockDim.x;
  for (size_t q = (size_t)blockIdx.x * blockDim.x + threadIdx.x; q < NNL / 4; q += stride) {
    const size_t i0 = q * 4;
    const int row = (int)(i0 >> 12);
    const int col0 = (int)(i0 & 4095);
    float4 lv = ((const float4*)L)[q];
    float lvv[4] = {lv.x, lv.y, lv.z, lv.w};
    bf16x4 tb;
    unsigned int p8 = 0;
#pragma unroll
    for (int e = 0; e < 4; ++e) {
      float v = lvv[e] - ((col0 + e == row) ? 1.0f : 0.0f);
      tb[e] = (bf16_t)v;
      p8 |= (unsigned int)f32_to_e4m3(v) << (8 * e);
    }
    *(bf16x4*)(T1 + i0) = tb;
    *(unsigned int*)(T1f8 + i0) = p8;
  }
}

// ---------------------------------------------------------------------------
// T2 = 2*T1*T1 - I, lower-triangular 128-grid (528 blocks).
// TRIPLE-BUFFERED K-loop with counted vmcnt (T4 mechanism): loads issued 2
// iters ahead; per-iter wait = vmcnt(4) (next iter's 4 loads stay in flight),
// never 0 except last iter. One s_barrier per iter. Invariant: each wave
// crosses the barrier only after ITS buffer-k loads landed => after the
// barrier ALL buffer-k loads landed; buffer k+2 (== k-1 mod 3) was last read
// in iter k-1 which every wave finished before this barrier.
// ---------------------------------------------------------------------------
__global__ __launch_bounds__(256, 3) void cheb_t2(
    const bf16_t* __restrict__ T1, bf16_t* __restrict__ T2,
    u8_t* __restrict__ T2f8) {
  __shared__ union {
    struct { bf16_t A[3][BM][BK]; bf16_t B[3][BM][BK]; } g;  // 48 KiB
    bf16_t tr[4][64 * 68];                                   // 34 KiB
  } sm;

  const int t = threadIdx.x;
  const int l = t & 63;
  const int w = t >> 6;

  const int bid0 = blockIdx.x;
  const int wid = (bid0 & 7) * 66 + (bid0 >> 3);   // 528 = 8*66, bijective
  int bm = (int)((sqrtf(8.0f * (float)wid + 1.0f) - 1.0f) * 0.5f);
  while (bm * (bm + 1) / 2 > wid) --bm;
  while ((bm + 1) * (bm + 2) / 2 <= wid) ++bm;
  const int bn = wid - bm * (bm + 1) / 2;
  const int m0 = bm * BM;
  const int n0 = bn * BM;
  const bool offd = (bm != bn);

  const int wr = (w >> 1) * 64;
  const int wc = (w & 1) * 64;
  const int lr = l >> 4;
  const int lc = l & 15;

  auto stage = [&](int buf, int kt) {
    const bf16_t* ga = T1 + (size_t)m0 * NV + kt * BK;
    const bf16_t* gb = T1 + (size_t)n0 * NV + kt * BK;
#pragma unroll
    for (int r = 0; r < 2; ++r) {
      int off = r * 256 + t;
      int row = off >> 2, c8 = off & 3;
      __builtin_amdgcn_global_load_lds(
          (const __attribute__((address_space(1))) unsigned int*)(ga + (size_t)row * NV + c8 * 8),
          (__attribute__((address_space(3))) unsigned int*)(&sm.g.A[buf][row][c8 * 8]),
          16, 0, 0);
      __builtin_amdgcn_global_load_lds(
          (const __attribute__((address_space(1))) unsigned int*)(gb + (size_t)row * NV + c8 * 8),
          (__attribute__((address_space(3))) unsigned int*)(&sm.g.B[buf][row][c8 * 8]),
          16, 0, 0);
    }
  };

  f32x4 acc[4][4] = {};

  stage(0, 0);
  stage(1, 1);
  int cur = 0;
  for (int kt = 0; kt < NKT; ++kt) {
    if (kt + 1 < NKT) { asm volatile("s_waitcnt vmcnt(4)" ::: "memory"); }
    else              { asm volatile("s_waitcnt vmcnt(0)" ::: "memory"); }
    __builtin_amdgcn_sched_barrier(0);
    __builtin_amdgcn_s_barrier();
    __builtin_amdgcn_sched_barrier(0);
    if (kt + 2 < NKT) {
      int nb = cur + 2; if (nb >= 3) nb -= 3;
      stage(nb, kt + 2);
    }
    bf16x8 a[4], b[4];
#pragma unroll
    for (int m = 0; m < 4; ++m)
      a[m] = *(const bf16x8*)&sm.g.A[cur][wr + m * 16 + lc][lr * 8];
#pragma unroll
    for (int n = 0; n < 4; ++n)
      b[n] = *(const bf16x8*)&sm.g.B[cur][wc + n * 16 + lc][lr * 8];
#pragma unroll
    for (int n = 0; n < 4; ++n)
#pragma unroll
      for (int m = 0; m < 4; ++m)
        acc[n][m] = __builtin_amdgcn_mfma_f32_16x16x32_bf16(b[n], a[m], acc[n][m], 0, 0, 0);
    ++cur; if (cur == 3) cur = 0;
  }
  __builtin_amdgcn_s_barrier();   // all compute done before LDS overlay reuse

  const int R = m0 + wr + lc;
  const int Cb = n0 + wc + lr * 4;
#pragma unroll
  for (int m = 0; m < 4; ++m) {
    const int row = R + m * 16;
    const int row_l = lc + 16 * m;
#pragma unroll
    for (int n = 0; n < 4; ++n) {
      const int colb = Cb + n * 16;
      const size_t idx = (size_t)row * NV + colb;
      bf16x4 ov;
      unsigned int p8 = 0;
#pragma unroll
      for (int r = 0; r < 4; ++r) {
        float v = 2.0f * acc[n][m][r];
        if (row == colb + r) v -= 1.0f;
        ov[r] = (bf16_t)v;
        p8 |= (unsigned int)f32_to_e4m3(v) << (8 * r);
      }
      *(bf16x4*)(T2 + idx) = ov;
      *(unsigned int*)(T2f8 + idx) = p8;
      if (offd)
        *(bf16x4*)&sm.tr[w][row_l * 68 + lr * 4 + 16 * n] = ov;
    }
  }
  if (offd) {
    __syncthreads();
    bf16_t vals[64];
#pragma unroll
    for (int i = 0; i < 64; ++i) vals[i] = sm.tr[w][i * 68 + l];
    const size_t db = (size_t)(n0 + wc + l) * NV + m0 + wr;
#pragma unroll
    for (int c8 = 0; c8 < 8; ++c8) {
      bf16x8 v;
      unsigned long long p8 = 0ull;
#pragma unroll
      for (int e = 0; e < 8; ++e) {
        v[e] = vals[c8 * 8 + e];
        p8 |= (unsigned long long)f32_to_e4m3((float)vals[c8 * 8 + e]) << (8 * e);
      }
      *(bf16x8*)(T2 + db + c8 * 8) = v;
      *(unsigned long long*)(T2f8 + db + c8 * 8) = p8;
    }
  }
}

// ---------------------------------------------------------------------------
// Fused final dispatch (528 blocks): dual-output fp8 GEMM, BK=64, triple-
// buffered counted-vmcnt K-loop (6 loads/iter in flight for next iter),
// + direct out emission. Diag-tiles-last ordering kept from round 18.
// ---------------------------------------------------------------------------
__global__ __launch_bounds__(256, 3) void cheb_fused(
    const u8_t* __restrict__ T1f8, const u8_t* __restrict__ T2f8,
    const bf16_t* __restrict__ T1, const bf16_t* __restrict__ T2,
    float* __restrict__ out, FCF fc) {
  extern __shared__ __align__(16) char smem[];
  // K-loop: sA1 | sA2 | sB, each [3][128][64] fp8 (24 KiB) -> 72 KiB
  // epilogue: tr3h [4][64*34] bf16 (17 KiB) | tr4h           -> 35 KiB
  u8_t* sA1 = (u8_t*)smem;
  u8_t* sA2 = (u8_t*)(smem + 24576);
  u8_t* sB  = (u8_t*)(smem + 49152);
  bf16_t* tr3h = (bf16_t*)smem;
  bf16_t* tr4h = (bf16_t*)(smem + 17408);

  const int t = threadIdx.x;
  const int l = t & 63;
  const int w = t >> 6;

  // Tile map: [0,496) -> strictly-lower tiles (bm>bn), XCD-swizzled
  // (496 = 8*62, bijective); [496,528) -> diagonal tile (d,d).
  const int bid0 = blockIdx.x;
  int bm, bn;
  bool offd;
  if (bid0 < 496) {
    const int j = (bid0 & 7) * 62 + (bid0 >> 3);
    bm = (int)((1.0f + sqrtf(1.0f + 8.0f * (float)j)) * 0.5f);
    while (bm * (bm - 1) / 2 > j) --bm;
    while ((bm + 1) * bm / 2 <= j) ++bm;
    bn = j - bm * (bm - 1) / 2;
    offd = true;
  } else {
    bm = bn = bid0 - 496;
    offd = false;
  }
  const int m0 = bm * BM;
  const int n0 = bn * BM;

  const int wr = (w >> 1) * 64;
  const int wc = (w & 1) * 64;
  const int lr = l >> 4;
  const int lc = l & 15;

  // Stage one 8 KiB panel (128 rows x 64B): 2 gload_lds per thread.
  // Physical slot sp at row holds logical slot sp ^ ((row>>1)&3).
  auto stageP = [&](u8_t* dst, const u8_t* srcRow, int buf, int kt) {
#pragma unroll
    for (int r = 0; r < 2; ++r) {
      const int idx = r * 256 + t;            // (row, phys slot) pair
      const int row = idx >> 2, sp = idx & 3;
      const int sl = sp ^ ((row >> 1) & 3);
      __builtin_amdgcn_global_load_lds(
          (const __attribute__((address_space(1))) unsigned int*)(srcRow + (size_t)row * NV + kt * 64 + sl * 16),
          (__attribute__((address_space(3))) unsigned int*)(dst + buf * 8192 + idx * 16),
          16, 0, 0);
    }
  };
  const u8_t* a1row = T1f8 + (size_t)m0 * NV;
  const u8_t* a2row = T2f8 + (size_t)m0 * NV;
  const u8_t* brow  = T2f8 + (size_t)n0 * NV;

  f32x4 acc3[4][4] = {};
  f32x4 acc4[4][4] = {};

  stageP(sA1, a1row, 0, 0);
  stageP(sA2, a2row, 0, 0);
  stageP(sB,  brow,  0, 0);
  stageP(sA1, a1row, 1, 1);
  stageP(sA2, a2row, 1, 1);
  stageP(sB,  brow,  1, 1);

  // swizzled read offset for logical (row, chunk kk, lane lr)
  auto swzoff = [&](int row, int kk) -> int {
    const int sl = kk * 2 + (lr >> 1);
    return row * 64 + ((sl ^ ((row >> 1) & 3)) << 4) + (lr & 1) * 8;
  };

  int cur = 0;
  for (int kt = 0; kt < 64; ++kt) {
    if (kt + 1 < 64) { asm volatile("s_waitcnt vmcnt(6)" ::: "memory"); }
    else             { asm volatile("s_waitcnt vmcnt(0)" ::: "memory"); }
    __builtin_amdgcn_sched_barrier(0);
    __builtin_amdgcn_s_barrier();
    __builtin_amdgcn_sched_barrier(0);
    if (kt + 2 < 64) {
      int nb = cur + 2; if (nb >= 3) nb -= 3;
      stageP(sA1, a1row, nb, kt + 2);
      stageP(sA2, a2row, nb, kt + 2);
      stageP(sB,  brow,  nb, kt + 2);
    }
#pragma unroll
    for (int kk = 0; kk < 2; ++kk) {
      i64_t b[4];
#pragma unroll
      for (int n = 0; n < 4; ++n)
        b[n] = *(const i64_t*)&sB[cur * 8192 + swzoff(wc + n * 16 + lc, kk)];
#pragma unroll
      for (int m = 0; m < 4; ++m) {
        const int oa = cur * 8192 + swzoff(wr + m * 16 + lc, kk);
        i64_t a1 = *(const i64_t*)&sA1[oa];
        i64_t a2 = *(const i64_t*)&sA2[oa];
#pragma unroll
        for (int n = 0; n < 4; ++n) {
          acc3[n][m] = __builtin_amdgcn_mfma_f32_16x16x32_fp8_fp8(b[n], a1, acc3[n][m], 0, 0, 0);
          acc4[n][m] = __builtin_amdgcn_mfma_f32_16x16x32_fp8_fp8(b[n], a2, acc4[n][m], 0, 0, 0);
        }
      }
    }
    ++cur; if (cur == 3) cur = 0;
  }
  __builtin_amdgcn_s_barrier();   // all compute done before LDS overlay reuse

  const int R = m0 + wr + lc;
  const int Cb = n0 + wc + lr * 4;

#pragma unroll
  for (int h = 0; h < 2; ++h) {
    // ---- stash half h: t3 = 2*acc3 - T1, t4 = 2*acc4 - I (bf16) ----
#pragma unroll
    for (int m = 0; m < 4; ++m) {
      const int row = R + m * 16;
      const int row_l = lc + 16 * m;
#pragma unroll
      for (int nn = 0; nn < 2; ++nn) {
        const int n = 2 * h + nn;
        const int colb = Cb + n * 16;
        const size_t idx = (size_t)row * NV + colb;
        bf16x4 t1v = *(const bf16x4*)(T1 + idx);
        bf16x4 o3, o4;
#pragma unroll
        for (int r = 0; r < 4; ++r) {
          o3[r] = (bf16_t)(2.0f * acc3[n][m][r] - (float)t1v[r]);
          float v4 = 2.0f * acc4[n][m][r];
          if (row == colb + r) v4 -= 1.0f;
          o4[r] = (bf16_t)v4;
        }
        const int lo = w * 2176 + row_l * 34 + nn * 16 + lr * 4;
        *(bf16x4*)&tr3h[lo] = o3;
        *(bf16x4*)&tr4h[lo] = o4;
      }
    }

    // ---- direct pass (i,j): 16 rows x 4 lanes x 8 f32 -> 128B segments ----
#pragma unroll
    for (int p = 0; p < 4; ++p) {
      const int r_l = p * 16 + (l >> 2);
      const int c_h = (l & 3) * 8;
      const int row_g = m0 + wr + r_l;
      const int col_g = n0 + wc + h * 32 + c_h;
      const size_t gb = (size_t)row_g * NV + col_g;
      const int lb = w * 2176 + r_l * 34 + c_h;
      bf16x4 t3a = *(const bf16x4*)&tr3h[lb];
      bf16x4 t3b = *(const bf16x4*)&tr3h[lb + 4];
      bf16x4 t4a = *(const bf16x4*)&tr4h[lb];
      bf16x4 t4b = *(const bf16x4*)&tr4h[lb + 4];
      bf16x8 t1v = *(const bf16x8*)(T1 + gb);
      bf16x8 t2v = *(const bf16x8*)(T2 + gb);
      float t3s[8], t4s[8];
#pragma unroll
      for (int e = 0; e < 4; ++e) {
        t3s[e] = (float)t3a[e]; t3s[e + 4] = (float)t3b[e];
        t4s[e] = (float)t4a[e]; t4s[e + 4] = (float)t4b[e];
      }
      const int d = row_g - col_g;
#pragma unroll
      for (int f = 0; f < 4; ++f) {
        float ot[8];
#pragma unroll
        for (int e = 0; e < 8; ++e)
          ot[e] = fc.c1[f] * (float)t1v[e] + fc.c2[f] * (float)t2v[e] +
                  fc.c3[f] * t3s[e] + fc.c4[f] * t4s[e];
        if (d >= 0 && d < 8) ot[d] += fc.cd[f];
        float4 o0, o1;
        o0.x = ot[0]; o0.y = ot[1]; o0.z = ot[2]; o0.w = ot[3];
        o1.x = ot[4]; o1.y = ot[5]; o1.z = ot[6]; o1.w = ot[7];
        float* op = out + (size_t)f * NNL + gb;
        *(float4*)op = o0;
        *(float4*)(op + 4) = o1;
      }
    }

    // ---- mirror pass (j,i): 8 rows x 8 lanes x 8 f32 -> 256B segments ----
    if (offd) {
#pragma unroll
      for (int p = 0; p < 4; ++p) {
        const int rr = p * 8 + (l >> 3);
        const int cc = (l & 7) * 8;
        const int row_g = n0 + wc + h * 32 + rr;
        const int col_g = m0 + wr + cc;
        const size_t gb = (size_t)row_g * NV + col_g;
        float t3s[8], t4s[8];
#pragma unroll
        for (int e = 0; e < 8; ++e) {
          t3s[e] = (float)tr3h[w * 2176 + (cc + e) * 34 + rr];
          t4s[e] = (float)tr4h[w * 2176 + (cc + e) * 34 + rr];
        }
        bf16x8 t1v = *(const bf16x8*)(T1 + gb);
        bf16x8 t2v = *(const bf16x8*)(T2 + gb);
#pragma unroll
        for (int f = 0; f < 4; ++f) {
          float ot[8];
#pragma unroll
          for (int e = 0; e < 8; ++e)
            ot[e] = fc.c1[f] * (float)t1v[e] + fc.c2[f] * (float)t2v[e] +
                    fc.c3[f] * t3s[e] + fc.c4[f] * t4s[e];
          float4 o0, o1;
          o0.x = ot[0]; o0.y = ot[1]; o0.z = ot[2]; o0.w = ot[3];
          o1.x = ot[4]; o1.y = ot[5]; o1.z = ot[6]; o1.w = ot[7];
          float* op = out + (size_t)f * NNL + gb;
          *(float4*)op = o0;
          *(float4*)(op + 4) = o1;
        }
      }
    }
  }
}

// ---------------------------------------------------------------------------
extern "C" void kernel_launch(void* const* d_in, const int* in_sizes, int n_in,
                              void* d_out, int out_size, void* d_ws, size_t ws_size,
                              hipStream_t stream) {
  const float* L = (const float*)d_in[0];
  float* out = (float*)d_out;

  // Chebyshev coefficients (host, double precision, Nc=33 nodes as in the
  // reference), pre-scaled by sqrt(N)=64. K=4 + fp8 operands proven
  // (rounds 15-18: absmax 0.541 vs threshold 0.785).
  const double taus[4] = {0.5, 1.0, 2.0, 4.0};
  float C[5][4];
  for (int o = 0; o < 5; ++o)
    for (int f = 0; f < 4; ++f) {
      double s = 0.0;
      for (int j = 0; j < 33; ++j) {
        double th = M_PI * (j + 0.5) / 33.0;
        s += cos(o * th) * exp(-taus[f] * (cos(th) + 1.0));
      }
      C[o][f] = (float)((2.0 / 33.0) * s * 64.0);
    }
  FCF fc;
  for (int f = 0; f < 4; ++f) {
    fc.c1[f] = C[1][f];
    fc.c2[f] = C[2][f];
    fc.c3[f] = C[3][f];
    fc.c4[f] = C[4][f];
    fc.cd[f] = 0.5f * C[0][f];
  }

  hipFuncSetAttribute(reinterpret_cast<const void*>(cheb_fused),
                      hipFuncAttributeMaxDynamicSharedMemorySize, 73728);

  // workspace: T1 bf16 (32M) | T2 bf16 (32M) | T1 fp8 (16M) | T2 fp8 (16M)
  const size_t bufB = NNL * sizeof(bf16_t);
  char* ws = (char*)d_ws;
  bf16_t* T1b = (bf16_t*)(ws + 0 * bufB);
  bf16_t* T2b = (bf16_t*)(ws + 1 * bufB);
  u8_t* T1f8 = (u8_t*)(ws + 2 * bufB);
  u8_t* T2f8 = (u8_t*)(ws + 2 * bufB + NNL);

  hipLaunchKernelGGL(init_kernel, dim3(2048), dim3(256), 0, stream, L, T1b, T1f8);

  // T2 = 2*T1^2 - I  (bf16 operands; dual-stores bf16 + fp8 planes)
  hipLaunchKernelGGL(cheb_t2, dim3(528), dim3(256), 0, stream,
                     (const bf16_t*)T1b, T2b, T2f8);

  // Dual GEMM on swizzled fp8 operands, BK=64, counted-vmcnt triple buffer
  hipLaunchKernelGGL(cheb_fused, dim3(528), dim3(256), 73728, stream,
                     (const u8_t*)T1f8, (const u8_t*)T2f8,
                     (const bf16_t*)T1b, (const bf16_t*)T2b, out, fc);
}

// Round 20
// 319.538 us; speedup vs baseline: 1.0659x; 1.0659x over previous
//
#include <hip/hip_runtime.h>
#include <hip/hip_fp8.h>
#include <math.h>

#define NV 4096
#define NNL ((size_t)NV * NV)
#define BM 128
#define BK 32
#define NKT (NV / BK)

typedef __bf16 bf16_t;
typedef __bf16 bf16x4 __attribute__((ext_vector_type(4)));
typedef __bf16 bf16x8 __attribute__((ext_vector_type(8)));
typedef float f32x4 __attribute__((ext_vector_type(4)));
typedef long i64_t;
typedef unsigned char u8_t;

struct FCF { float c1[4], c2[4], c3[4], c4[4], cd[4]; };

__device__ __forceinline__ u8_t f32_to_e4m3(float v) {
  return (u8_t)__hip_cvt_float_to_fp8(v, __HIP_SATFINITE, __HIP_E4M3);
}

// ---------------------------------------------------------------------------
// Init: T1 = L - I  (bf16 plane + fp8-e4m3 plane for GEMM operands)
// ---------------------------------------------------------------------------
__global__ __launch_bounds__(256) void init_kernel(const float* __restrict__ L,
                                                   bf16_t* __restrict__ T1,
                                                   u8_t* __restrict__ T1f8) {
  const size_t stride = (size_t)gridDim.x * blockDim.x;
  for (size_t q = (size_t)blockIdx.x * blockDim.x + threadIdx.x; q < NNL / 4; q += stride) {
    const size_t i0 = q * 4;
    const int row = (int)(i0 >> 12);
    const int col0 = (int)(i0 & 4095);
    float4 lv = ((const float4*)L)[q];
    float lvv[4] = {lv.x, lv.y, lv.z, lv.w};
    bf16x4 tb;
    unsigned int p8 = 0;
#pragma unroll
    for (int e = 0; e < 4; ++e) {
      float v = lvv[e] - ((col0 + e == row) ? 1.0f : 0.0f);
      tb[e] = (bf16_t)v;
      p8 |= (unsigned int)f32_to_e4m3(v) << (8 * e);
    }
    *(bf16x4*)(T1 + i0) = tb;
    *(unsigned int*)(T1f8 + i0) = p8;
  }
}

// ---------------------------------------------------------------------------
// T2 = 2*T1*T1 - I, lower-triangular 128-grid (528 blocks), proven structure.
// bf16 operands (keeps T2 accurate); epilogue dual-stores bf16 + fp8 planes.
// ---------------------------------------------------------------------------
__global__ __launch_bounds__(256, 3) void cheb_t2(
    const bf16_t* __restrict__ T1, bf16_t* __restrict__ T2,
    u8_t* __restrict__ T2f8) {
  __shared__ union {
    struct { bf16_t A[2][BM][BK]; bf16_t B[2][BM][BK]; } g;  // 32 KiB
    bf16_t tr[4][64 * 68];                                   // 34 KiB
  } sm;

  const int t = threadIdx.x;
  const int l = t & 63;
  const int w = t >> 6;

  const int bid0 = blockIdx.x;
  const int wid = (bid0 & 7) * 66 + (bid0 >> 3);   // 528 = 8*66, bijective
  int bm = (int)((sqrtf(8.0f * (float)wid + 1.0f) - 1.0f) * 0.5f);
  while (bm * (bm + 1) / 2 > wid) --bm;
  while ((bm + 1) * (bm + 2) / 2 <= wid) ++bm;
  const int bn = wid - bm * (bm + 1) / 2;
  const int m0 = bm * BM;
  const int n0 = bn * BM;
  const bool offd = (bm != bn);

  const int wr = (w >> 1) * 64;
  const int wc = (w & 1) * 64;
  const int lr = l >> 4;
  const int lc = l & 15;

  auto stage = [&](int buf, int kt) {
    const bf16_t* ga = T1 + (size_t)m0 * NV + kt * BK;
    const bf16_t* gb = T1 + (size_t)n0 * NV + kt * BK;
#pragma unroll
    for (int r = 0; r < 2; ++r) {
      int off = r * 256 + t;
      int row = off >> 2, c8 = off & 3;
      __builtin_amdgcn_global_load_lds(
          (const __attribute__((address_space(1))) unsigned int*)(ga + (size_t)row * NV + c8 * 8),
          (__attribute__((address_space(3))) unsigned int*)(&sm.g.A[buf][row][c8 * 8]),
          16, 0, 0);
      __builtin_amdgcn_global_load_lds(
          (const __attribute__((address_space(1))) unsigned int*)(gb + (size_t)row * NV + c8 * 8),
          (__attribute__((address_space(3))) unsigned int*)(&sm.g.B[buf][row][c8 * 8]),
          16, 0, 0);
    }
  };

  f32x4 acc[4][4] = {};

  stage(0, 0);
  __syncthreads();

  for (int kt = 0; kt < NKT; ++kt) {
    int cur = kt & 1;
    if (kt + 1 < NKT) stage(cur ^ 1, kt + 1);
    bf16x8 a[4], b[4];
#pragma unroll
    for (int m = 0; m < 4; ++m)
      a[m] = *(const bf16x8*)&sm.g.A[cur][wr + m * 16 + lc][lr * 8];
#pragma unroll
    for (int n = 0; n < 4; ++n)
      b[n] = *(const bf16x8*)&sm.g.B[cur][wc + n * 16 + lc][lr * 8];
#pragma unroll
    for (int n = 0; n < 4; ++n)
#pragma unroll
      for (int m = 0; m < 4; ++m)
        acc[n][m] = __builtin_amdgcn_mfma_f32_16x16x32_bf16(b[n], a[m], acc[n][m], 0, 0, 0);
    __syncthreads();
  }

  const int R = m0 + wr + lc;
  const int Cb = n0 + wc + lr * 4;
#pragma unroll
  for (int m = 0; m < 4; ++m) {
    const int row = R + m * 16;
    const int row_l = lc + 16 * m;
#pragma unroll
    for (int n = 0; n < 4; ++n) {
      const int colb = Cb + n * 16;
      const size_t idx = (size_t)row * NV + colb;
      bf16x4 ov;
      unsigned int p8 = 0;
#pragma unroll
      for (int r = 0; r < 4; ++r) {
        float v = 2.0f * acc[n][m][r];
        if (row == colb + r) v -= 1.0f;
        ov[r] = (bf16_t)v;
        p8 |= (unsigned int)f32_to_e4m3(v) << (8 * r);
      }
      *(bf16x4*)(T2 + idx) = ov;
      *(unsigned int*)(T2f8 + idx) = p8;
      if (offd)
        *(bf16x4*)&sm.tr[w][row_l * 68 + lr * 4 + 16 * n] = ov;
    }
  }
  if (offd) {
    __syncthreads();
    bf16_t vals[64];
#pragma unroll
    for (int i = 0; i < 64; ++i) vals[i] = sm.tr[w][i * 68 + l];
    const size_t db = (size_t)(n0 + wc + l) * NV + m0 + wr;
#pragma unroll
    for (int c8 = 0; c8 < 8; ++c8) {
      bf16x8 v;
      unsigned long long p8 = 0ull;
#pragma unroll
      for (int e = 0; e < 8; ++e) {
        v[e] = vals[c8 * 8 + e];
        p8 |= (unsigned long long)f32_to_e4m3((float)vals[c8 * 8 + e]) << (8 * e);
      }
      *(bf16x8*)(T2 + db + c8 * 8) = v;
      *(unsigned long long*)(T2f8 + db + c8 * 8) = p8;
    }
  }
}

// ---------------------------------------------------------------------------
// Fused final dispatch (528 blocks): dual-output fp8 GEMM, BK=64, + direct
// out emission. Diag-tiles-last ordering. (Round-18 configuration — the
// session's best; counted-vmcnt/triple-buffer variants regressed.)
// ---------------------------------------------------------------------------
__global__ __launch_bounds__(256, 3) void cheb_fused(
    const u8_t* __restrict__ T1f8, const u8_t* __restrict__ T2f8,
    const bf16_t* __restrict__ T1, const bf16_t* __restrict__ T2,
    float* __restrict__ out, FCF fc) {
  extern __shared__ __align__(16) char smem[];
  // K-loop: sA1 | sA2 | sB, each [2][128][64] fp8 (16 KiB) -> 48 KiB
  // epilogue: tr3h [4][64*34] bf16 (17 KiB) | tr4h           -> 35 KiB
  u8_t* sA1 = (u8_t*)smem;
  u8_t* sA2 = (u8_t*)(smem + 16384);
  u8_t* sB  = (u8_t*)(smem + 32768);
  bf16_t* tr3h = (bf16_t*)smem;
  bf16_t* tr4h = (bf16_t*)(smem + 17408);

  const int t = threadIdx.x;
  const int l = t & 63;
  const int w = t >> 6;

  // Tile map: [0,496) -> strictly-lower tiles (bm>bn), XCD-swizzled
  // (496 = 8*62, bijective); [496,528) -> diagonal tile (d,d).
  const int bid0 = blockIdx.x;
  int bm, bn;
  bool offd;
  if (bid0 < 496) {
    const int j = (bid0 & 7) * 62 + (bid0 >> 3);
    bm = (int)((1.0f + sqrtf(1.0f + 8.0f * (float)j)) * 0.5f);
    while (bm * (bm - 1) / 2 > j) --bm;
    while ((bm + 1) * bm / 2 <= j) ++bm;
    bn = j - bm * (bm - 1) / 2;
    offd = true;
  } else {
    bm = bn = bid0 - 496;
    offd = false;
  }
  const int m0 = bm * BM;
  const int n0 = bn * BM;

  const int wr = (w >> 1) * 64;
  const int wc = (w & 1) * 64;
  const int lr = l >> 4;
  const int lc = l & 15;

  // Stage one 8 KiB panel (128 rows x 64B): 2 gload_lds per thread.
  // Physical slot sp at row holds logical slot sp ^ ((row>>1)&3).
  auto stageP = [&](u8_t* dst, const u8_t* srcRow, int buf, int kt) {
#pragma unroll
    for (int r = 0; r < 2; ++r) {
      const int idx = r * 256 + t;            // (row, phys slot) pair
      const int row = idx >> 2, sp = idx & 3;
      const int sl = sp ^ ((row >> 1) & 3);
      __builtin_amdgcn_global_load_lds(
          (const __attribute__((address_space(1))) unsigned int*)(srcRow + (size_t)row * NV + kt * 64 + sl * 16),
          (__attribute__((address_space(3))) unsigned int*)(dst + buf * 8192 + idx * 16),
          16, 0, 0);
    }
  };
  const u8_t* a1row = T1f8 + (size_t)m0 * NV;
  const u8_t* a2row = T2f8 + (size_t)m0 * NV;
  const u8_t* brow  = T2f8 + (size_t)n0 * NV;

  f32x4 acc3[4][4] = {};
  f32x4 acc4[4][4] = {};

  stageP(sA1, a1row, 0, 0);
  stageP(sA2, a2row, 0, 0);
  stageP(sB,  brow,  0, 0);
  __syncthreads();

  // swizzled read offset for logical (row, chunk kk, lane lr)
  auto swzoff = [&](int row, int kk) -> int {
    const int sl = kk * 2 + (lr >> 1);
    return row * 64 + ((sl ^ ((row >> 1) & 3)) << 4) + (lr & 1) * 8;
  };

  for (int kt = 0; kt < 64; ++kt) {
    int cur = kt & 1;
    if (kt + 1 < 64) {
      stageP(sA1, a1row, cur ^ 1, kt + 1);
      stageP(sA2, a2row, cur ^ 1, kt + 1);
      stageP(sB,  brow,  cur ^ 1, kt + 1);
    }
#pragma unroll
    for (int kk = 0; kk < 2; ++kk) {
      i64_t b[4];
#pragma unroll
      for (int n = 0; n < 4; ++n)
        b[n] = *(const i64_t*)&sB[cur * 8192 + swzoff(wc + n * 16 + lc, kk)];
#pragma unroll
      for (int m = 0; m < 4; ++m) {
        const int oa = cur * 8192 + swzoff(wr + m * 16 + lc, kk);
        i64_t a1 = *(const i64_t*)&sA1[oa];
        i64_t a2 = *(const i64_t*)&sA2[oa];
#pragma unroll
        for (int n = 0; n < 4; ++n) {
          acc3[n][m] = __builtin_amdgcn_mfma_f32_16x16x32_fp8_fp8(b[n], a1, acc3[n][m], 0, 0, 0);
          acc4[n][m] = __builtin_amdgcn_mfma_f32_16x16x32_fp8_fp8(b[n], a2, acc4[n][m], 0, 0, 0);
        }
      }
    }
    __syncthreads();
  }
  // tr buffers are PER-WAVE; same-wave DS ordering suffices past this point.

  const int R = m0 + wr + lc;
  const int Cb = n0 + wc + lr * 4;

#pragma unroll
  for (int h = 0; h < 2; ++h) {
    // ---- stash half h: t3 = 2*acc3 - T1, t4 = 2*acc4 - I (bf16) ----
#pragma unroll
    for (int m = 0; m < 4; ++m) {
      const int row = R + m * 16;
      const int row_l = lc + 16 * m;
#pragma unroll
      for (int nn = 0; nn < 2; ++nn) {
        const int n = 2 * h + nn;
        const int colb = Cb + n * 16;
        const size_t idx = (size_t)row * NV + colb;
        bf16x4 t1v = *(const bf16x4*)(T1 + idx);
        bf16x4 o3, o4;
#pragma unroll
        for (int r = 0; r < 4; ++r) {
          o3[r] = (bf16_t)(2.0f * acc3[n][m][r] - (float)t1v[r]);
          float v4 = 2.0f * acc4[n][m][r];
          if (row == colb + r) v4 -= 1.0f;
          o4[r] = (bf16_t)v4;
        }
        const int lo = w * 2176 + row_l * 34 + nn * 16 + lr * 4;
        *(bf16x4*)&tr3h[lo] = o3;
        *(bf16x4*)&tr4h[lo] = o4;
      }
    }

    // ---- direct pass (i,j): 16 rows x 4 lanes x 8 f32 -> 128B segments ----
#pragma unroll
    for (int p = 0; p < 4; ++p) {
      const int r_l = p * 16 + (l >> 2);
      const int c_h = (l & 3) * 8;
      const int row_g = m0 + wr + r_l;
      const int col_g = n0 + wc + h * 32 + c_h;
      const size_t gb = (size_t)row_g * NV + col_g;
      const int lb = w * 2176 + r_l * 34 + c_h;
      bf16x4 t3a = *(const bf16x4*)&tr3h[lb];
      bf16x4 t3b = *(const bf16x4*)&tr3h[lb + 4];
      bf16x4 t4a = *(const bf16x4*)&tr4h[lb];
      bf16x4 t4b = *(const bf16x4*)&tr4h[lb + 4];
      bf16x8 t1v = *(const bf16x8*)(T1 + gb);
      bf16x8 t2v = *(const bf16x8*)(T2 + gb);
      float t3s[8], t4s[8];
#pragma unroll
      for (int e = 0; e < 4; ++e) {
        t3s[e] = (float)t3a[e]; t3s[e + 4] = (float)t3b[e];
        t4s[e] = (float)t4a[e]; t4s[e + 4] = (float)t4b[e];
      }
      const int d = row_g - col_g;
#pragma unroll
      for (int f = 0; f < 4; ++f) {
        float ot[8];
#pragma unroll
        for (int e = 0; e < 8; ++e)
          ot[e] = fc.c1[f] * (float)t1v[e] + fc.c2[f] * (float)t2v[e] +
                  fc.c3[f] * t3s[e] + fc.c4[f] * t4s[e];
        if (d >= 0 && d < 8) ot[d] += fc.cd[f];
        float4 o0, o1;
        o0.x = ot[0]; o0.y = ot[1]; o0.z = ot[2]; o0.w = ot[3];
        o1.x = ot[4]; o1.y = ot[5]; o1.z = ot[6]; o1.w = ot[7];
        float* op = out + (size_t)f * NNL + gb;
        *(float4*)op = o0;
        *(float4*)(op + 4) = o1;
      }
    }

    // ---- mirror pass (j,i): 8 rows x 8 lanes x 8 f32 -> 256B segments ----
    if (offd) {
#pragma unroll
      for (int p = 0; p < 4; ++p) {
        const int rr = p * 8 + (l >> 3);
        const int cc = (l & 7) * 8;
        const int row_g = n0 + wc + h * 32 + rr;
        const int col_g = m0 + wr + cc;
        const size_t gb = (size_t)row_g * NV + col_g;
        float t3s[8], t4s[8];
#pragma unroll
        for (int e = 0; e < 8; ++e) {
          t3s[e] = (float)tr3h[w * 2176 + (cc + e) * 34 + rr];
          t4s[e] = (float)tr4h[w * 2176 + (cc + e) * 34 + rr];
        }
        bf16x8 t1v = *(const bf16x8*)(T1 + gb);
        bf16x8 t2v = *(const bf16x8*)(T2 + gb);
#pragma unroll
        for (int f = 0; f < 4; ++f) {
          float ot[8];
#pragma unroll
          for (int e = 0; e < 8; ++e)
            ot[e] = fc.c1[f] * (float)t1v[e] + fc.c2[f] * (float)t2v[e] +
                    fc.c3[f] * t3s[e] + fc.c4[f] * t4s[e];
          float4 o0, o1;
          o0.x = ot[0]; o0.y = ot[1]; o0.z = ot[2]; o0.w = ot[3];
          o1.x = ot[4]; o1.y = ot[5]; o1.z = ot[6]; o1.w = ot[7];
          float* op = out + (size_t)f * NNL + gb;
          *(float4*)op = o0;
          *(float4*)(op + 4) = o1;
        }
      }
    }
  }
}

// ---------------------------------------------------------------------------
extern "C" void kernel_launch(void* const* d_in, const int* in_sizes, int n_in,
                              void* d_out, int out_size, void* d_ws, size_t ws_size,
                              hipStream_t stream) {
  const float* L = (const float*)d_in[0];
  float* out = (float*)d_out;

  // Chebyshev coefficients (host, double precision, Nc=33 nodes as in the
  // reference), pre-scaled by sqrt(N)=64. K=4 + fp8 operands proven
  // (rounds 15-19: absmax 0.541 vs threshold 0.785).
  const double taus[4] = {0.5, 1.0, 2.0, 4.0};
  float C[5][4];
  for (int o = 0; o < 5; ++o)
    for (int f = 0; f < 4; ++f) {
      double s = 0.0;
      for (int j = 0; j < 33; ++j) {
        double th = M_PI * (j + 0.5) / 33.0;
        s += cos(o * th) * exp(-taus[f] * (cos(th) + 1.0));
      }
      C[o][f] = (float)((2.0 / 33.0) * s * 64.0);
    }
  FCF fc;
  for (int f = 0; f < 4; ++f) {
    fc.c1[f] = C[1][f];
    fc.c2[f] = C[2][f];
    fc.c3[f] = C[3][f];
    fc.c4[f] = C[4][f];
    fc.cd[f] = 0.5f * C[0][f];
  }

  hipFuncSetAttribute(reinterpret_cast<const void*>(cheb_fused),
                      hipFuncAttributeMaxDynamicSharedMemorySize, 49152);

  // workspace: T1 bf16 (32M) | T2 bf16 (32M) | T1 fp8 (16M) | T2 fp8 (16M)
  const size_t bufB = NNL * sizeof(bf16_t);
  char* ws = (char*)d_ws;
  bf16_t* T1b = (bf16_t*)(ws + 0 * bufB);
  bf16_t* T2b = (bf16_t*)(ws + 1 * bufB);
  u8_t* T1f8 = (u8_t*)(ws + 2 * bufB);
  u8_t* T2f8 = (u8_t*)(ws + 2 * bufB + NNL);

  hipLaunchKernelGGL(init_kernel, dim3(2048), dim3(256), 0, stream, L, T1b, T1f8);

  // T2 = 2*T1^2 - I  (bf16 operands; dual-stores bf16 + fp8 planes)
  hipLaunchKernelGGL(cheb_t2, dim3(528), dim3(256), 0, stream,
                     (const bf16_t*)T1b, T2b, T2f8);

  // Dual GEMM on swizzled fp8 operands, BK=64, diag-tiles-last ordering
  hipLaunchKernelGGL(cheb_fused, dim3(528), dim3(256), 49152, stream,
                     (const u8_t*)T1f8, (const u8_t*)T2f8,
                     (const bf16_t*)T1b, (const bf16_t*)T2b, out, fc);
}